// Round 13
// baseline (415.651 us; speedup 1.0000x reference)
//
#include <hip/hip_runtime.h>
#include <hip/hip_bf16.h>
#include <math.h>

#define S_LEN 2048
#define HID 2560
#define NH 8
#define NKV 4
#define HD 256
#define WINDOW 1024

typedef short short8 __attribute__((ext_vector_type(8)));
typedef short short4_t __attribute__((ext_vector_type(4)));
typedef float f32x4 __attribute__((ext_vector_type(4)));
typedef float float4_t __attribute__((ext_vector_type(4)));

__device__ __forceinline__ short bf16_rne(float x) {
  unsigned u = __float_as_uint(x);
  return (short)((u + 0x7FFFu + ((u >> 16) & 1u)) >> 16);
}
__device__ __forceinline__ void split2(float x, short &h, short &l) {
  unsigned u = __float_as_uint(x);
  unsigned hb = (u + 0x7FFFu + ((u >> 16) & 1u)) & 0xFFFF0000u;
  h = (short)(hb >> 16);
  float r = x - __uint_as_float(hb);
  l = bf16_rne(r);
}

// async global->LDS, 16B per lane, wave-uniform LDS base (dest = base+lane*16)
__device__ __forceinline__ void gload16(const short* g, short* l) {
  __builtin_amdgcn_global_load_lds(
      (const __attribute__((address_space(1))) void*)g,
      (__attribute__((address_space(3))) void*)l, 16, 0, 0);
}

// ================= pre-split GEMM body, product count by MODE =============
// MODE bit0: + Al*Bh (A split).  bit1: + Ah*Bl (B split).  Always Ah*Bh.
// Tile 64(M)x128(N)x64(K), 256 thr / 4 waves. global_load_lds width=16
// staging: linear LDS dest + pre-swizzled global source + SWZ read.
// qkv GEMM runs at ~919 TF effective = the 2-phase structure's ceiling
// (m99-m141: source pipelining null; 8-phase infeasible: hi/lo dbuf LDS
// = 256KB > 160KB). Done here.
#define SWZ(g, r) ((((g) ^ ((r) & 7))) * 8)
template <int MODE>
__device__ __forceinline__ void gemm_body(
    const short* __restrict__ Ah, const short* __restrict__ Al,
    const short* __restrict__ Bh, const short* __restrict__ Bl,
    float* __restrict__ C, int Klen, int Kstr, int ldc, int m0, int n0, int tid,
    short (*__restrict__ Ahs)[64], short (*__restrict__ Als)[64],
    short (*__restrict__ Bhs)[64], short (*__restrict__ Bls)[64]) {
  constexpr bool USE_AL = (MODE & 1) != 0;
  constexpr bool USE_BL = (MODE & 2) != 0;
  const int wv = tid >> 6, lane = tid & 63;
  const int wm = (wv >> 1) * 32, wn = (wv & 1) * 64;
  const int quad = lane >> 4, col = lane & 15;
  // per-lane staging source geometry (8-row chunks keep row&7 == lane>>3)
  const int lr = lane >> 3;
  const size_t lgofs = (size_t)(((lane & 7) ^ lr)) * 8;
  const size_t aBase = (size_t)(m0 + lr) * Kstr + lgofs;
  const size_t bBase = (size_t)(n0 + lr) * Kstr + lgofs;

  f32x4 acc[2][4];
#pragma unroll
  for (int i = 0; i < 2; i++)
#pragma unroll
    for (int j = 0; j < 4; j++) acc[i][j] = (f32x4){0.f, 0.f, 0.f, 0.f};

  for (int k0 = 0; k0 < Klen; k0 += 64) {
#pragma unroll
    for (int c = wv; c < 8; c += 4) {
      const size_t go = aBase + (size_t)c * 8 * Kstr + k0;
      gload16(Ah + go, &Ahs[c * 8][0]);
      if (USE_AL) gload16(Al + go, &Als[c * 8][0]);
    }
#pragma unroll
    for (int c = wv; c < 16; c += 4) {
      const size_t go = bBase + (size_t)c * 8 * Kstr + k0;
      gload16(Bh + go, &Bhs[c * 8][0]);
      if (USE_BL) gload16(Bl + go, &Bls[c * 8][0]);
    }
    __syncthreads();
#pragma unroll
    for (int ks = 0; ks < 2; ks++) {
      const int g = ks * 4 + quad;
      short8 afh[2], afl[2], bfh[4], bfl[4];
#pragma unroll
      for (int i = 0; i < 2; i++) {
        int ar = wm + i * 16 + col;
        afh[i] = *reinterpret_cast<const short8*>(&Ahs[ar][SWZ(g, ar)]);
        if (USE_AL)
          afl[i] = *reinterpret_cast<const short8*>(&Als[ar][SWZ(g, ar)]);
      }
#pragma unroll
      for (int j = 0; j < 4; j++) {
        int br = wn + j * 16 + col;
        bfh[j] = *reinterpret_cast<const short8*>(&Bhs[br][SWZ(g, br)]);
        if (USE_BL)
          bfl[j] = *reinterpret_cast<const short8*>(&Bls[br][SWZ(g, br)]);
      }
#pragma unroll
      for (int i = 0; i < 2; i++)
#pragma unroll
        for (int j = 0; j < 4; j++) {
          acc[i][j] = __builtin_amdgcn_mfma_f32_16x16x32_bf16(afh[i], bfh[j], acc[i][j], 0, 0, 0);
          if (USE_BL)
            acc[i][j] = __builtin_amdgcn_mfma_f32_16x16x32_bf16(afh[i], bfl[j], acc[i][j], 0, 0, 0);
          if (USE_AL)
            acc[i][j] = __builtin_amdgcn_mfma_f32_16x16x32_bf16(afl[i], bfh[j], acc[i][j], 0, 0, 0);
        }
    }
    __syncthreads();
  }
#pragma unroll
  for (int i = 0; i < 2; i++)
#pragma unroll
    for (int j = 0; j < 4; j++)
#pragma unroll
      for (int r = 0; r < 4; r++)
        C[(size_t)(m0 + wm + i * 16 + quad * 4 + r) * ldc + n0 + wn + j * 16 + col] =
            acc[i][j][r];
}

// merged qkv projection: blocks [0,256) = v MODE2, [256,1024) = qk MODE3.
__global__ __launch_bounds__(256, 3)
void gemm_qkv(const short* __restrict__ Ah, const short* __restrict__ Al,
              const short* __restrict__ qkvTh, const short* __restrict__ qkvTl,
              float* __restrict__ Cqkv) {
  __shared__ short Ahs[64][64];
  __shared__ short Als[64][64];
  __shared__ short Bhs[128][64];
  __shared__ short Bls[128][64];
  const int b = blockIdx.x;
  if (b < 256) {
    gemm_body<2>(Ah, Al, qkvTh + (size_t)3072 * HID, qkvTl + (size_t)3072 * HID,
                 Cqkv + 3072, HID, HID, 4096, (b / 8) * 64, (b % 8) * 128,
                 threadIdx.x, Ahs, Als, Bhs, Bls);
  } else {
    const int t = b - 256;
    gemm_body<3>(Ah, Al, qkvTh, qkvTl, Cqkv, HID, HID, 4096, (t / 24) * 64,
                 (t % 24) * 128, threadIdx.x, Ahs, Als, Bhs, Bls);
  }
}

// out projection, 128x160 tile (round-13): 16m x 16n = EXACTLY 256 blocks =
// 1/CU balanced (round-12's 320-block 128x128 ran 1.25/CU: 64 CUs did 2
// serial blocks while 192 idled -> ~2x makespan). 56 KB LDS. Per wave:
// 64x80 output (4x5 frags), acc 80 VGPR + ~60 operand VGPR < 256 at (256,2).
__global__ __launch_bounds__(256, 2)
void gemm_out160(const short* __restrict__ ctxh, const short* __restrict__ woTh,
                 const short* __restrict__ woTl, float* __restrict__ C) {
  __shared__ short Ahs[128][64];   // 16 KB
  __shared__ short Bhs[160][64];   // 20 KB
  __shared__ short Bls[160][64];   // 20 KB
  const int tid = threadIdx.x;
  const int wv = tid >> 6, lane = tid & 63;
  const int wm = (wv >> 1) * 64, wn = (wv & 1) * 80;
  const int quad = lane >> 4, col = lane & 15;
  const int m0 = (blockIdx.x >> 4) * 128, n0 = (blockIdx.x & 15) * 160;
  const int lr = lane >> 3;
  const size_t lgofs = (size_t)(((lane & 7) ^ lr)) * 8;
  const size_t aBase = (size_t)(m0 + lr) * 2048 + lgofs;
  const size_t bBase = (size_t)(n0 + lr) * 2048 + lgofs;

  f32x4 acc[4][5];
#pragma unroll
  for (int i = 0; i < 4; i++)
#pragma unroll
    for (int j = 0; j < 5; j++) acc[i][j] = (f32x4){0.f, 0.f, 0.f, 0.f};

  for (int k0 = 0; k0 < 2048; k0 += 64) {
#pragma unroll
    for (int c = wv; c < 16; c += 4)
      gload16(ctxh + aBase + (size_t)c * 8 * 2048 + k0, &Ahs[c * 8][0]);
#pragma unroll
    for (int c = wv; c < 20; c += 4) {
      const size_t gb = bBase + (size_t)c * 8 * 2048 + k0;
      gload16(woTh + gb, &Bhs[c * 8][0]);
      gload16(woTl + gb, &Bls[c * 8][0]);
    }
    __syncthreads();
#pragma unroll
    for (int ks = 0; ks < 2; ks++) {
      const int g = ks * 4 + quad;
      short8 afh[4], bfh[5], bfl[5];
#pragma unroll
      for (int i = 0; i < 4; i++) {
        int ar = wm + i * 16 + col;
        afh[i] = *reinterpret_cast<const short8*>(&Ahs[ar][SWZ(g, ar)]);
      }
#pragma unroll
      for (int j = 0; j < 5; j++) {
        int br = wn + j * 16 + col;
        bfh[j] = *reinterpret_cast<const short8*>(&Bhs[br][SWZ(g, br)]);
        bfl[j] = *reinterpret_cast<const short8*>(&Bls[br][SWZ(g, br)]);
      }
#pragma unroll
      for (int i = 0; i < 4; i++)
#pragma unroll
        for (int j = 0; j < 5; j++) {
          acc[i][j] = __builtin_amdgcn_mfma_f32_16x16x32_bf16(afh[i], bfh[j], acc[i][j], 0, 0, 0);
          acc[i][j] = __builtin_amdgcn_mfma_f32_16x16x32_bf16(afh[i], bfl[j], acc[i][j], 0, 0, 0);
        }
    }
    __syncthreads();
  }
#pragma unroll
  for (int i = 0; i < 4; i++)
#pragma unroll
    for (int j = 0; j < 5; j++)
#pragma unroll
      for (int r = 0; r < 4; r++)
        C[(size_t)(m0 + wm + i * 16 + quad * 4 + r) * HID + n0 + wn + j * 16 + col] =
            acc[i][j][r];
}

// ================= merged prep: hs split + all weight splitT =================
__device__ __forceinline__ void wsplitT_body(const float* __restrict__ W,
                                             short* __restrict__ WTh,
                                             short* __restrict__ WTl,
                                             int KW, int NW, int n_ofs,
                                             int k0, int n0, int tid,
                                             float (*T)[65]) {
  const int r = tid >> 4, c4 = (tid & 15) * 4;
#pragma unroll
  for (int p = 0; p < 4; p++) {
    float4_t v = *reinterpret_cast<const float4_t*>(
        &W[(size_t)(k0 + r + p * 16) * NW + n0 + c4]);
#pragma unroll
    for (int e = 0; e < 4; e++) T[r + p * 16][c4 + e] = v[e];
  }
  __syncthreads();
  const int gk = tid & 7;  // k-granule within row (8 shorts)
#pragma unroll
  for (int pass = 0; pass < 2; pass++) {
    const int n_loc = (tid >> 3) + pass * 32;
    short8 hv, lv;
#pragma unroll
    for (int e = 0; e < 8; e++) {
      short hh, ll;
      split2(T[gk * 8 + e][n_loc], hh, ll);
      hv[e] = hh; lv[e] = ll;
    }
    size_t base = (size_t)(n_ofs + n0 + n_loc) * KW + k0 + gk * 8;
    *reinterpret_cast<short8*>(WTh + base) = hv;
    *reinterpret_cast<short8*>(WTl + base) = lv;
  }
}

__global__ __launch_bounds__(256)
void prep_kernel(const float* __restrict__ hs, const float* __restrict__ wq,
                 const float* __restrict__ wk, const float* __restrict__ wv,
                 const float* __restrict__ wo, short* __restrict__ Ah,
                 short* __restrict__ Al, short* __restrict__ qkvTh,
                 short* __restrict__ qkvTl, short* __restrict__ woTh,
                 short* __restrict__ woTl) {
  __shared__ float T[64][65];
  const int bx = blockIdx.x;
  const int tid = threadIdx.x;
  if (bx < 5120) {
    const int i = bx * 256 + tid;  // n4 = 2048*2560/4 = 1310720 = 5120*256 exact
    float4_t v = reinterpret_cast<const float4_t*>(hs)[i];
    short4_t h, l;
#pragma unroll
    for (int e = 0; e < 4; e++) {
      short hh, ll;
      split2(v[e], hh, ll);
      h[e] = hh; l[e] = ll;
    }
    reinterpret_cast<short4_t*>(Ah)[i] = h;
    reinterpret_cast<short4_t*>(Al)[i] = l;
  } else if (bx < 6400) {
    const int local = bx - 5120;
    wsplitT_body(wq, qkvTh, qkvTl, HID, 2048, 0, (local % 40) * 64,
                 (local / 40) * 64, tid, T);
  } else if (bx < 7040) {
    const int local = bx - 6400;
    wsplitT_body(wk, qkvTh, qkvTl, HID, 1024, 2048, (local % 40) * 64,
                 (local / 40) * 64, tid, T);
  } else if (bx < 7680) {
    const int local = bx - 7040;
    wsplitT_body(wv, qkvTh, qkvTl, HID, 1024, 3072, (local % 40) * 64,
                 (local / 40) * 64, tid, T);
  } else {
    const int local = bx - 7680;
    wsplitT_body(wo, woTh, woTl, 2048, HID, 0, (local % 32) * 64,
                 (local / 32) * 64, tid, T);
  }
}

// ================= merged k/v norms, wave-per-row ==========================
__global__ __launch_bounds__(256)
void norm_kernel(const float* __restrict__ Cqkv, const float* __restrict__ kw,
                 const float* __restrict__ cosb, const float* __restrict__ sinb,
                 short* __restrict__ kh, short* __restrict__ kl,
                 short* __restrict__ vtb) {
  const int unit = blockIdx.x * 4 + (threadIdx.x >> 6);
  const int u = unit & 7;
  const int sq = unit >> 3;
  const int t = threadIdx.x & 63;
  const int d = t * 4;
  const int colbase = (u < 4) ? 2048 + u * HD : 3072 + (u - 4) * HD;
  const float4_t x = *reinterpret_cast<const float4_t*>(
      &Cqkv[(size_t)sq * 4096 + colbase + d]);
  float v = x[0] * x[0] + x[1] * x[1] + x[2] * x[2] + x[3] * x[3];
#pragma unroll
  for (int off = 32; off; off >>= 1) v += __shfl_xor(v, off);
  const float scale = rsqrtf(v * (1.0f / HD) + 1e-6f);
  if (u < 4) {
    const float4_t w = *reinterpret_cast<const float4_t*>(kw + d);
    const float4_t cb = *reinterpret_cast<const float4_t*>(
        &cosb[(size_t)sq * HD + d]);
    const float4_t sb = *reinterpret_cast<const float4_t*>(
        &sinb[(size_t)sq * HD + d]);
    const float sgn = (t < 32) ? -1.f : 1.f;
    short4_t hv, lv;
#pragma unroll
    for (int e = 0; e < 4; e++) {
      const float n = x[e] * scale * w[e];
      const float other = __shfl_xor(n, 32);
      const float r = n * cb[e] + sgn * other * sb[e];
      short hh, ll;
      split2(r, hh, ll);
      hv[e] = hh; lv[e] = ll;
    }
    const size_t b = ((size_t)sq * NKV + u) * HD + d;
    *reinterpret_cast<short4_t*>(kh + b) = hv;
    *reinterpret_cast<short4_t*>(kl + b) = lv;
  } else {
    const int hh = u - 4;
#pragma unroll
    for (int e = 0; e < 4; e++)
      vtb[((size_t)hh * HD + d + e) * S_LEN + sq] = bf16_rne(x[e] * scale);
  }
}

// ================= flash attention (swizzled LDS, 2 blocks/CU) =============
// NOTE: needs >=128 VGPR; keep (256,2). No XCD swizzle (round-5 regression).
// Round-12 measured: 6-chain QK split + setprio = -4.9 us (kept).
#define KSW(g, r) (((g) ^ ((r) & 7)) * 8)
#define VSW(g, d) ((((g) + ((d) >> 1)) & 3) * 8)
__global__ __launch_bounds__(256, 2)
void flash_attn2(const float* __restrict__ qn, int qrs,
                 const float* __restrict__ qw, const float* __restrict__ cosb,
                 const float* __restrict__ sinb,
                 const short* __restrict__ kh, const short* __restrict__ kl,
                 const short* __restrict__ vtb, float* __restrict__ oA,
                 float* __restrict__ oB, float* __restrict__ mlA,
                 float* __restrict__ mlB) {
  __shared__ short Kh[32][256], Kl[32][256];  // 32 KB
  __shared__ short Vb[256][32];               // 16 KB
  __shared__ short Ps[64][32];                // 4 KB   (total 53248 B)
  const int qt = blockIdx.x, h = blockIdx.y, sp = blockIdx.z;
  const int kvh = h >> 1;
  const int q0 = qt * 64;
  const int tid = threadIdx.x;
  const int w = tid >> 6, lane = tid & 63;
  const int quad = lane >> 4, col = lane & 15;
  float* oOut = sp ? oB : oA;
  float* mlOut = sp ? mlB : mlA;
  short8 qh[8], ql[8];
  {
    const int sq = q0 + w * 16 + col;
    const float* qrow = qn + (size_t)sq * qrs + h * HD;
    float xq[8][8];
    float ssum = 0.f;
#pragma unroll
    for (int s8 = 0; s8 < 8; s8++) {
      const int d0 = s8 * 32 + quad * 8;
      float4_t a = *reinterpret_cast<const float4_t*>(qrow + d0);
      float4_t b = *reinterpret_cast<const float4_t*>(qrow + d0 + 4);
#pragma unroll
      for (int e = 0; e < 4; e++) {
        xq[s8][e] = a[e];
        xq[s8][4 + e] = b[e];
        ssum += a[e] * a[e] + b[e] * b[e];
      }
    }
    ssum += __shfl_xor(ssum, 16);
    ssum += __shfl_xor(ssum, 32);
    const float scale = rsqrtf(ssum * (1.0f / HD) + 1e-6f);
#pragma unroll
    for (int s8 = 0; s8 < 8; s8++) {
      const int d0 = s8 * 32 + quad * 8;
      float4_t w0 = *reinterpret_cast<const float4_t*>(qw + d0);
      float4_t w1 = *reinterpret_cast<const float4_t*>(qw + d0 + 4);
#pragma unroll
      for (int e = 0; e < 4; e++) {
        xq[s8][e] *= scale * w0[e];
        xq[s8][4 + e] *= scale * w1[e];
      }
    }
    const float* crow = cosb + (size_t)sq * HD;
    const float* srow = sinb + (size_t)sq * HD;
#pragma unroll
    for (int s8 = 0; s8 < 8; s8++) {
      const int d0 = s8 * 32 + quad * 8;
      float4_t c0 = *reinterpret_cast<const float4_t*>(crow + d0);
      float4_t c1 = *reinterpret_cast<const float4_t*>(crow + d0 + 4);
      float4_t s0 = *reinterpret_cast<const float4_t*>(srow + d0);
      float4_t s1 = *reinterpret_cast<const float4_t*>(srow + d0 + 4);
      const float sgn = (s8 < 4) ? -1.f : 1.f;
      const int pp = s8 ^ 4;
#pragma unroll
      for (int e = 0; e < 4; e++) {
        short hh, ll;
        split2(xq[s8][e] * c0[e] + sgn * xq[pp][e] * s0[e], hh, ll);
        qh[s8][e] = hh; ql[s8][e] = ll;
        split2(xq[s8][4 + e] * c1[e] + sgn * xq[pp][4 + e] * s1[e], hh, ll);
        qh[s8][4 + e] = hh; ql[s8][4 + e] = ll;
      }
    }
  }
  f32x4 o[16];
#pragma unroll
  for (int i = 0; i < 16; i++) o[i] = (f32x4){0.f, 0.f, 0.f, 0.f};
  float m_r[4] = {-INFINITY, -INFINITY, -INFINITY, -INFINITY};
  float l_r[4] = {0.f, 0.f, 0.f, 0.f};
  const int lo_t = (q0 > 1023) ? ((q0 - 1023) >> 5) : 0;
  const int hi_t = (q0 + 63) >> 5;
  const int halfn = (hi_t - lo_t + 2) >> 1;
  const int t0 = sp ? (lo_t + halfn) : lo_t;
  const int t1 = sp ? hi_t : (lo_t + halfn - 1);
  for (int kt = t0; kt <= t1; kt++) {
    const int kt0 = kt << 5;
    __syncthreads();
#pragma unroll
    for (int i = 0; i < 4; i++) {
      int idx = tid + i * 256;
      int row = idx >> 5, g = idx & 31;
      size_t gofs = ((size_t)(kt0 + row) * NKV + kvh) * HD + g * 8;
      *reinterpret_cast<short8*>(&Kh[row][KSW(g, row)]) =
          *reinterpret_cast<const short8*>(kh + gofs);
      *reinterpret_cast<short8*>(&Kl[row][KSW(g, row)]) =
          *reinterpret_cast<const short8*>(kl + gofs);
    }
#pragma unroll
    for (int i = 0; i < 4; i++) {
      int idx = tid + i * 256;
      int d = idx >> 2, g = idx & 3;
      *reinterpret_cast<short8*>(&Vb[d][VSW(g, d)]) =
          *reinterpret_cast<const short8*>(
              vtb + ((size_t)kvh * HD + d) * S_LEN + kt0 + g * 8);
    }
    __syncthreads();
    // QK^T with 6 independent MFMA chains: schh/schl/sclh x 2 nt
    f32x4 schh[2], schl[2], sclh[2];
#pragma unroll
    for (int nt = 0; nt < 2; nt++) {
      schh[nt] = (f32x4){0.f, 0.f, 0.f, 0.f};
      schl[nt] = (f32x4){0.f, 0.f, 0.f, 0.f};
      sclh[nt] = (f32x4){0.f, 0.f, 0.f, 0.f};
    }
    __builtin_amdgcn_s_setprio(1);
#pragma unroll
    for (int s8 = 0; s8 < 8; s8++) {
#pragma unroll
      for (int nt = 0; nt < 2; nt++) {
        const int br = nt * 16 + col;
        const short8 bh = *reinterpret_cast<const short8*>(
            &Kh[br][KSW(s8 * 4 + quad, br)]);
        const short8 bl = *reinterpret_cast<const short8*>(
            &Kl[br][KSW(s8 * 4 + quad, br)]);
        schh[nt] = __builtin_amdgcn_mfma_f32_16x16x32_bf16(qh[s8], bh, schh[nt], 0, 0, 0);
        schl[nt] = __builtin_amdgcn_mfma_f32_16x16x32_bf16(qh[s8], bl, schl[nt], 0, 0, 0);
        sclh[nt] = __builtin_amdgcn_mfma_f32_16x16x32_bf16(ql[s8], bh, sclh[nt], 0, 0, 0);
      }
    }
    __builtin_amdgcn_s_setprio(0);
    f32x4 sc[2];
#pragma unroll
    for (int nt = 0; nt < 2; nt++) sc[nt] = schh[nt] + schl[nt] + sclh[nt];
#pragma unroll
    for (int r = 0; r < 4; r++) {
      const int q_abs = q0 + w * 16 + quad * 4 + r;
      const int prow = w * 16 + quad * 4 + r;
#pragma unroll
      for (int nt = 0; nt < 2; nt++) {
        int k_abs = kt0 + nt * 16 + col;
        bool valid = (k_abs <= q_abs) && (q_abs - k_abs < WINDOW);
        if (!valid) sc[nt][r] = -INFINITY;
      }
      float mx = fmaxf(sc[0][r], sc[1][r]);
      mx = fmaxf(mx, __shfl_xor(mx, 1));
      mx = fmaxf(mx, __shfl_xor(mx, 2));
      mx = fmaxf(mx, __shfl_xor(mx, 4));
      mx = fmaxf(mx, __shfl_xor(mx, 8));
      // defer-max (T13): only rescale when the max moved by >8
      if (!__all(mx <= m_r[r] + 8.f)) {
        const float mn = fmaxf(m_r[r], mx);
        const float alpha = (mn == -INFINITY) ? 1.f : __expf(m_r[r] - mn);
        m_r[r] = mn;
        l_r[r] *= alpha;
#pragma unroll
        for (int nt2 = 0; nt2 < 16; nt2++) o[nt2][r] *= alpha;
      }
      float rsum = 0.f;
#pragma unroll
      for (int nt = 0; nt < 2; nt++) {
        float s = sc[nt][r];
        float e = (s == -INFINITY) ? 0.f : __expf(s - m_r[r]);
        rsum += e;
        int ge = nt * 2 + (col >> 3);
        Ps[prow][VSW(ge, prow) + (col & 7)] = bf16_rne(e);
      }
      rsum += __shfl_xor(rsum, 1);
      rsum += __shfl_xor(rsum, 2);
      rsum += __shfl_xor(rsum, 4);
      rsum += __shfl_xor(rsum, 8);
      l_r[r] += rsum;
    }
    __syncthreads();
    {
      const int prow = w * 16 + col;
      const short8 pa = *reinterpret_cast<const short8*>(&Ps[prow][VSW(quad, prow)]);
      __builtin_amdgcn_s_setprio(1);
#pragma unroll
      for (int nt = 0; nt < 16; nt++) {
        const int vr = nt * 16 + col;
        const short8 vb = *reinterpret_cast<const short8*>(&Vb[vr][VSW(quad, vr)]);
        o[nt] = __builtin_amdgcn_mfma_f32_16x16x32_bf16(pa, vb, o[nt], 0, 0, 0);
      }
      __builtin_amdgcn_s_setprio(0);
    }
  }
#pragma unroll
  for (int r = 0; r < 4; r++) {
    const int row = q0 + w * 16 + quad * 4 + r;
    const size_t base = ((size_t)row * NH + h) * HD;
#pragma unroll
    for (int nt = 0; nt < 16; nt++) oOut[base + nt * 16 + col] = o[nt][r];
    if (col == 0) {
      mlOut[((size_t)row * NH + h) * 2] = m_r[r];
      mlOut[((size_t)row * NH + h) * 2 + 1] = l_r[r];
    }
  }
}

// merge the two k-splits -> single-bf16 ctx (out-proj A operand)
__global__ __launch_bounds__(256)
void combine_kernel(const float* __restrict__ oA, const float* __restrict__ oB,
                    const float* __restrict__ mlA, const float* __restrict__ mlB,
                    short* __restrict__ ctxh) {
  const int unit = blockIdx.x * 8 + (threadIdx.x >> 5);
  const int t = threadIdx.x & 31;
  const float mA = mlA[(size_t)unit * 2], lA = mlA[(size_t)unit * 2 + 1];
  const float mB = mlB[(size_t)unit * 2], lB = mlB[(size_t)unit * 2 + 1];
  const float m = fmaxf(mA, mB);
  const float eA = (mA == -INFINITY) ? 0.f : __expf(mA - m);
  const float eB = (mB == -INFINITY) ? 0.f : __expf(mB - m);
  const float inv = 1.0f / (eA * lA + eB * lB);
  const size_t b = (size_t)unit * HD + t * 8;
  const float4_t a0 = *reinterpret_cast<const float4_t*>(oA + b);
  const float4_t a1 = *reinterpret_cast<const float4_t*>(oA + b + 4);
  const float4_t b0 = *reinterpret_cast<const float4_t*>(oB + b);
  const float4_t b1 = *reinterpret_cast<const float4_t*>(oB + b + 4);
  short8 out;
#pragma unroll
  for (int e = 0; e < 4; e++) {
    out[e] = bf16_rne((eA * a0[e] + eB * b0[e]) * inv);
    out[4 + e] = bf16_rne((eA * a1[e] + eB * b1[e]) * inv);
  }
  *reinterpret_cast<short8*>(ctxh + b) = out;
}

extern "C" void kernel_launch(void* const* d_in, const int* in_sizes, int n_in,
                              void* d_out, int out_size, void* d_ws, size_t ws_size,
                              hipStream_t stream) {
  const float* hs   = (const float*)d_in[0];
  const float* cosb = (const float*)d_in[1];
  const float* sinb = (const float*)d_in[2];
  const float* wq   = (const float*)d_in[3];
  const float* wk   = (const float*)d_in[4];
  const float* wv   = (const float*)d_in[5];
  const float* wo   = (const float*)d_in[6];
  const float* qw   = (const float*)d_in[7];
  const float* kw   = (const float*)d_in[8];
  dim3 blk(256);

  const size_t szAh   = (size_t)S_LEN * HID * 2;       // 10.49 MB
  const size_t szQKVT = (size_t)4096 * HID * 2;        // 20.97 MB
  const size_t szWoT  = (size_t)HID * 2048 * 2;        // 10.49 MB
  const size_t szCqkv = (size_t)S_LEN * 4096 * 4;      // 33.55 MB
  const size_t szKh   = (size_t)S_LEN * NKV * HD * 2;  // 4.19 MB
  const size_t szMl   = (size_t)S_LEN * NH * 2 * 4;    // 131 KB

  char* p = (char*)d_ws + 256;
  short* Ah    = (short*)p;  p += szAh;    // later: oA fp32 (16.8 MB <= Ah+Al 21 MB)
  short* Al    = (short*)p;  p += szAh;
  short* qkvTh = (short*)p;  p += szQKVT;  // later: ctxh bf16 (8.4 MB)
  short* qkvTl = (short*)p;  p += szQKVT;
  short* woTh  = (short*)p;  p += szWoT;
  short* woTl  = (short*)p;  p += szWoT;
  float* Cqkv  = (float*)p;  p += szCqkv;
  short* kh    = (short*)p;  p += szKh;
  short* kl    = (short*)p;  p += szKh;
  short* vtb   = (short*)p;  p += szKh;
  float* mlA   = (float*)p;  p += szMl;
  float* mlB   = (float*)p;  p += szMl;
  float* oA    = (float*)Ah;      // alias: Ah/Al dead after GEMMs
  float* oB    = (float*)d_out;   // dead until out-proj
  short* ctxh  = qkvTh;           // alias: qkvT dead after qkv GEMM

  // merged prep: hs split + wq/wk/wv/wo splitT
  prep_kernel<<<8960, blk, 0, stream>>>(hs, wq, wk, wv, wo, Ah, Al, qkvTh,
                                        qkvTl, woTh, woTl);
  // merged qkv projection (v MODE2 first, then qk MODE3; 1024 blocks)
  gemm_qkv<<<1024, blk, 0, stream>>>(Ah, Al, qkvTh, qkvTl, Cqkv);
  // merged k/v norms, wave-per-row
  norm_kernel<<<4096, blk, 0, stream>>>(Cqkv, kw, cosb, sinb, kh, kl, vtb);
  // flash attention (split-k x2), q-norm+rope fused, 6-chain QK + setprio
  flash_attn2<<<dim3(S_LEN / 64, NH, 2), blk, 0, stream>>>(
      Cqkv, 4096, qw, cosb, sinb, kh, kl, vtb, oA, oB, mlA, mlB);
  combine_kernel<<<2048, blk, 0, stream>>>(oA, oB, mlA, mlB, ctxh);
  // out projection: 128x160 tile, exactly 256 blocks = 1/CU balanced
  gemm_out160<<<256, blk, 0, stream>>>(ctxh, woTh, woTl, (float*)d_out);
}

// Round 14
// 408.566 us; speedup vs baseline: 1.0173x; 1.0173x over previous
//
#include <hip/hip_runtime.h>
#include <hip/hip_bf16.h>
#include <math.h>

#define S_LEN 2048
#define HID 2560
#define NH 8
#define NKV 4
#define HD 256
#define WINDOW 1024

typedef short short8 __attribute__((ext_vector_type(8)));
typedef short short4_t __attribute__((ext_vector_type(4)));
typedef float f32x4 __attribute__((ext_vector_type(4)));
typedef float float4_t __attribute__((ext_vector_type(4)));

__device__ __forceinline__ short bf16_rne(float x) {
  unsigned u = __float_as_uint(x);
  return (short)((u + 0x7FFFu + ((u >> 16) & 1u)) >> 16);
}
__device__ __forceinline__ void split2(float x, short &h, short &l) {
  unsigned u = __float_as_uint(x);
  unsigned hb = (u + 0x7FFFu + ((u >> 16) & 1u)) & 0xFFFF0000u;
  h = (short)(hb >> 16);
  float r = x - __uint_as_float(hb);
  l = bf16_rne(r);
}

// async global->LDS, 16B per lane, wave-uniform LDS base (dest = base+lane*16)
__device__ __forceinline__ void gload16(const short* g, short* l) {
  __builtin_amdgcn_global_load_lds(
      (const __attribute__((address_space(1))) void*)g,
      (__attribute__((address_space(3))) void*)l, 16, 0, 0);
}

// ================= pre-split GEMM body, product count by MODE =============
// MODE bit0: + Al*Bh (A split).  bit1: + Ah*Bl (B split).  Always Ah*Bh.
// Tile 64(M)x128(N)x64(K), 256 thr / 4 waves. global_load_lds width=16
// staging: linear LDS dest + pre-swizzled global source + SWZ read.
// qkv GEMM runs at ~919 TF effective = the 2-phase structure's ceiling
// (m99-m141: source pipelining null; 8-phase infeasible: hi/lo dbuf LDS
// = 256KB > 160KB). Done here.
// Round-13 post-mortem: 128x160 out-proj retile was null (the 320-block
// 128x128 at (256,3)/48KB was already single-residency-wave: 320 < 768
// slots). Reverted to 128x128.
#define SWZ(g, r) ((((g) ^ ((r) & 7))) * 8)
template <int MODE>
__device__ __forceinline__ void gemm_body(
    const short* __restrict__ Ah, const short* __restrict__ Al,
    const short* __restrict__ Bh, const short* __restrict__ Bl,
    float* __restrict__ C, int Klen, int Kstr, int ldc, int m0, int n0, int tid,
    short (*__restrict__ Ahs)[64], short (*__restrict__ Als)[64],
    short (*__restrict__ Bhs)[64], short (*__restrict__ Bls)[64]) {
  constexpr bool USE_AL = (MODE & 1) != 0;
  constexpr bool USE_BL = (MODE & 2) != 0;
  const int wv = tid >> 6, lane = tid & 63;
  const int wm = (wv >> 1) * 32, wn = (wv & 1) * 64;
  const int quad = lane >> 4, col = lane & 15;
  // per-lane staging source geometry (8-row chunks keep row&7 == lane>>3)
  const int lr = lane >> 3;
  const size_t lgofs = (size_t)(((lane & 7) ^ lr)) * 8;
  const size_t aBase = (size_t)(m0 + lr) * Kstr + lgofs;
  const size_t bBase = (size_t)(n0 + lr) * Kstr + lgofs;

  f32x4 acc[2][4];
#pragma unroll
  for (int i = 0; i < 2; i++)
#pragma unroll
    for (int j = 0; j < 4; j++) acc[i][j] = (f32x4){0.f, 0.f, 0.f, 0.f};

  for (int k0 = 0; k0 < Klen; k0 += 64) {
#pragma unroll
    for (int c = wv; c < 8; c += 4) {
      const size_t go = aBase + (size_t)c * 8 * Kstr + k0;
      gload16(Ah + go, &Ahs[c * 8][0]);
      if (USE_AL) gload16(Al + go, &Als[c * 8][0]);
    }
#pragma unroll
    for (int c = wv; c < 16; c += 4) {
      const size_t go = bBase + (size_t)c * 8 * Kstr + k0;
      gload16(Bh + go, &Bhs[c * 8][0]);
      if (USE_BL) gload16(Bl + go, &Bls[c * 8][0]);
    }
    __syncthreads();
#pragma unroll
    for (int ks = 0; ks < 2; ks++) {
      const int g = ks * 4 + quad;
      short8 afh[2], afl[2], bfh[4], bfl[4];
#pragma unroll
      for (int i = 0; i < 2; i++) {
        int ar = wm + i * 16 + col;
        afh[i] = *reinterpret_cast<const short8*>(&Ahs[ar][SWZ(g, ar)]);
        if (USE_AL)
          afl[i] = *reinterpret_cast<const short8*>(&Als[ar][SWZ(g, ar)]);
      }
#pragma unroll
      for (int j = 0; j < 4; j++) {
        int br = wn + j * 16 + col;
        bfh[j] = *reinterpret_cast<const short8*>(&Bhs[br][SWZ(g, br)]);
        if (USE_BL)
          bfl[j] = *reinterpret_cast<const short8*>(&Bls[br][SWZ(g, br)]);
      }
#pragma unroll
      for (int i = 0; i < 2; i++)
#pragma unroll
        for (int j = 0; j < 4; j++) {
          acc[i][j] = __builtin_amdgcn_mfma_f32_16x16x32_bf16(afh[i], bfh[j], acc[i][j], 0, 0, 0);
          if (USE_BL)
            acc[i][j] = __builtin_amdgcn_mfma_f32_16x16x32_bf16(afh[i], bfl[j], acc[i][j], 0, 0, 0);
          if (USE_AL)
            acc[i][j] = __builtin_amdgcn_mfma_f32_16x16x32_bf16(afl[i], bfh[j], acc[i][j], 0, 0, 0);
        }
    }
    __syncthreads();
  }
#pragma unroll
  for (int i = 0; i < 2; i++)
#pragma unroll
    for (int j = 0; j < 4; j++)
#pragma unroll
      for (int r = 0; r < 4; r++)
        C[(size_t)(m0 + wm + i * 16 + quad * 4 + r) * ldc + n0 + wn + j * 16 + col] =
            acc[i][j][r];
}

// merged qkv projection: blocks [0,256) = v MODE2, [256,1024) = qk MODE3.
__global__ __launch_bounds__(256, 3)
void gemm_qkv(const short* __restrict__ Ah, const short* __restrict__ Al,
              const short* __restrict__ qkvTh, const short* __restrict__ qkvTl,
              float* __restrict__ Cqkv) {
  __shared__ short Ahs[64][64];
  __shared__ short Als[64][64];
  __shared__ short Bhs[128][64];
  __shared__ short Bls[128][64];
  const int b = blockIdx.x;
  if (b < 256) {
    gemm_body<2>(Ah, Al, qkvTh + (size_t)3072 * HID, qkvTl + (size_t)3072 * HID,
                 Cqkv + 3072, HID, HID, 4096, (b / 8) * 64, (b % 8) * 128,
                 threadIdx.x, Ahs, Als, Bhs, Bls);
  } else {
    const int t = b - 256;
    gemm_body<3>(Ah, Al, qkvTh, qkvTl, Cqkv, HID, HID, 4096, (t / 24) * 64,
                 (t % 24) * 128, threadIdx.x, Ahs, Als, Bhs, Bls);
  }
}

// out projection, 128x128 tile: 320 blocks, 48 KB LDS, single residency wave.
__global__ __launch_bounds__(256, 3)
void gemm_out128(const short* __restrict__ ctxh, const short* __restrict__ woTh,
                 const short* __restrict__ woTl, float* __restrict__ C) {
  __shared__ short Ahs[128][64];   // 16 KB
  __shared__ short Bhs[128][64];   // 16 KB
  __shared__ short Bls[128][64];   // 16 KB
  const int tid = threadIdx.x;
  const int wv = tid >> 6, lane = tid & 63;
  const int wm = (wv >> 1) * 64, wn = (wv & 1) * 64;
  const int quad = lane >> 4, col = lane & 15;
  const int m0 = (blockIdx.x / 20) * 128, n0 = (blockIdx.x % 20) * 128;
  const int lr = lane >> 3;
  const size_t lgofs = (size_t)(((lane & 7) ^ lr)) * 8;
  const size_t aBase = (size_t)(m0 + lr) * 2048 + lgofs;
  const size_t bBase = (size_t)(n0 + lr) * 2048 + lgofs;

  f32x4 acc[4][4];
#pragma unroll
  for (int i = 0; i < 4; i++)
#pragma unroll
    for (int j = 0; j < 4; j++) acc[i][j] = (f32x4){0.f, 0.f, 0.f, 0.f};

  for (int k0 = 0; k0 < 2048; k0 += 64) {
#pragma unroll
    for (int c = wv; c < 16; c += 4) {
      gload16(ctxh + aBase + (size_t)c * 8 * 2048 + k0, &Ahs[c * 8][0]);
      const size_t gb = bBase + (size_t)c * 8 * 2048 + k0;
      gload16(woTh + gb, &Bhs[c * 8][0]);
      gload16(woTl + gb, &Bls[c * 8][0]);
    }
    __syncthreads();
#pragma unroll
    for (int ks = 0; ks < 2; ks++) {
      const int g = ks * 4 + quad;
      short8 afh[4], bfh[4], bfl[4];
#pragma unroll
      for (int i = 0; i < 4; i++) {
        int ar = wm + i * 16 + col;
        afh[i] = *reinterpret_cast<const short8*>(&Ahs[ar][SWZ(g, ar)]);
      }
#pragma unroll
      for (int j = 0; j < 4; j++) {
        int br = wn + j * 16 + col;
        bfh[j] = *reinterpret_cast<const short8*>(&Bhs[br][SWZ(g, br)]);
        bfl[j] = *reinterpret_cast<const short8*>(&Bls[br][SWZ(g, br)]);
      }
#pragma unroll
      for (int i = 0; i < 4; i++)
#pragma unroll
        for (int j = 0; j < 4; j++) {
          acc[i][j] = __builtin_amdgcn_mfma_f32_16x16x32_bf16(afh[i], bfh[j], acc[i][j], 0, 0, 0);
          acc[i][j] = __builtin_amdgcn_mfma_f32_16x16x32_bf16(afh[i], bfl[j], acc[i][j], 0, 0, 0);
        }
    }
    __syncthreads();
  }
#pragma unroll
  for (int i = 0; i < 4; i++)
#pragma unroll
    for (int j = 0; j < 4; j++)
#pragma unroll
      for (int r = 0; r < 4; r++)
        C[(size_t)(m0 + wm + i * 16 + quad * 4 + r) * HID + n0 + wn + j * 16 + col] =
            acc[i][j][r];
}

// ================= merged prep: hs split + all weight splitT =================
__device__ __forceinline__ void wsplitT_body(const float* __restrict__ W,
                                             short* __restrict__ WTh,
                                             short* __restrict__ WTl,
                                             int KW, int NW, int n_ofs,
                                             int k0, int n0, int tid,
                                             float (*T)[65]) {
  const int r = tid >> 4, c4 = (tid & 15) * 4;
#pragma unroll
  for (int p = 0; p < 4; p++) {
    float4_t v = *reinterpret_cast<const float4_t*>(
        &W[(size_t)(k0 + r + p * 16) * NW + n0 + c4]);
#pragma unroll
    for (int e = 0; e < 4; e++) T[r + p * 16][c4 + e] = v[e];
  }
  __syncthreads();
  const int gk = tid & 7;  // k-granule within row (8 shorts)
#pragma unroll
  for (int pass = 0; pass < 2; pass++) {
    const int n_loc = (tid >> 3) + pass * 32;
    short8 hv, lv;
#pragma unroll
    for (int e = 0; e < 8; e++) {
      short hh, ll;
      split2(T[gk * 8 + e][n_loc], hh, ll);
      hv[e] = hh; lv[e] = ll;
    }
    size_t base = (size_t)(n_ofs + n0 + n_loc) * KW + k0 + gk * 8;
    *reinterpret_cast<short8*>(WTh + base) = hv;
    *reinterpret_cast<short8*>(WTl + base) = lv;
  }
}

__global__ __launch_bounds__(256)
void prep_kernel(const float* __restrict__ hs, const float* __restrict__ wq,
                 const float* __restrict__ wk, const float* __restrict__ wv,
                 const float* __restrict__ wo, short* __restrict__ Ah,
                 short* __restrict__ Al, short* __restrict__ qkvTh,
                 short* __restrict__ qkvTl, short* __restrict__ woTh,
                 short* __restrict__ woTl) {
  __shared__ float T[64][65];
  const int bx = blockIdx.x;
  const int tid = threadIdx.x;
  if (bx < 5120) {
    const int i = bx * 256 + tid;  // n4 = 2048*2560/4 = 1310720 = 5120*256 exact
    float4_t v = reinterpret_cast<const float4_t*>(hs)[i];
    short4_t h, l;
#pragma unroll
    for (int e = 0; e < 4; e++) {
      short hh, ll;
      split2(v[e], hh, ll);
      h[e] = hh; l[e] = ll;
    }
    reinterpret_cast<short4_t*>(Ah)[i] = h;
    reinterpret_cast<short4_t*>(Al)[i] = l;
  } else if (bx < 6400) {
    const int local = bx - 5120;
    wsplitT_body(wq, qkvTh, qkvTl, HID, 2048, 0, (local % 40) * 64,
                 (local / 40) * 64, tid, T);
  } else if (bx < 7040) {
    const int local = bx - 6400;
    wsplitT_body(wk, qkvTh, qkvTl, HID, 1024, 2048, (local % 40) * 64,
                 (local / 40) * 64, tid, T);
  } else if (bx < 7680) {
    const int local = bx - 7040;
    wsplitT_body(wv, qkvTh, qkvTl, HID, 1024, 3072, (local % 40) * 64,
                 (local / 40) * 64, tid, T);
  } else {
    const int local = bx - 7680;
    wsplitT_body(wo, woTh, woTl, 2048, HID, 0, (local % 32) * 64,
                 (local / 32) * 64, tid, T);
  }
}

// ================= merged k/v norms, wave-per-row ==========================
__global__ __launch_bounds__(256)
void norm_kernel(const float* __restrict__ Cqkv, const float* __restrict__ kw,
                 const float* __restrict__ cosb, const float* __restrict__ sinb,
                 short* __restrict__ kh, short* __restrict__ kl,
                 short* __restrict__ vtb) {
  const int unit = blockIdx.x * 4 + (threadIdx.x >> 6);
  const int u = unit & 7;
  const int sq = unit >> 3;
  const int t = threadIdx.x & 63;
  const int d = t * 4;
  const int colbase = (u < 4) ? 2048 + u * HD : 3072 + (u - 4) * HD;
  const float4_t x = *reinterpret_cast<const float4_t*>(
      &Cqkv[(size_t)sq * 4096 + colbase + d]);
  float v = x[0] * x[0] + x[1] * x[1] + x[2] * x[2] + x[3] * x[3];
#pragma unroll
  for (int off = 32; off; off >>= 1) v += __shfl_xor(v, off);
  const float scale = rsqrtf(v * (1.0f / HD) + 1e-6f);
  if (u < 4) {
    const float4_t w = *reinterpret_cast<const float4_t*>(kw + d);
    const float4_t cb = *reinterpret_cast<const float4_t*>(
        &cosb[(size_t)sq * HD + d]);
    const float4_t sb = *reinterpret_cast<const float4_t*>(
        &sinb[(size_t)sq * HD + d]);
    const float sgn = (t < 32) ? -1.f : 1.f;
    short4_t hv, lv;
#pragma unroll
    for (int e = 0; e < 4; e++) {
      const float n = x[e] * scale * w[e];
      const float other = __shfl_xor(n, 32);
      const float r = n * cb[e] + sgn * other * sb[e];
      short hh, ll;
      split2(r, hh, ll);
      hv[e] = hh; lv[e] = ll;
    }
    const size_t b = ((size_t)sq * NKV + u) * HD + d;
    *reinterpret_cast<short4_t*>(kh + b) = hv;
    *reinterpret_cast<short4_t*>(kl + b) = lv;
  } else {
    const int hh = u - 4;
#pragma unroll
    for (int e = 0; e < 4; e++)
      vtb[((size_t)hh * HD + d + e) * S_LEN + sq] = bf16_rne(x[e] * scale);
  }
}

// ================= flash attention (swizzled LDS, 2 blocks/CU) =============
// NOTE: needs >=128 VGPR; keep (256,2). No XCD swizzle (round-5 regression).
// Round-12 measured: 6-chain QK split + setprio = -4.9 us (kept).
#define KSW(g, r) (((g) ^ ((r) & 7)) * 8)
#define VSW(g, d) ((((g) + ((d) >> 1)) & 3) * 8)
__global__ __launch_bounds__(256, 2)
void flash_attn2(const float* __restrict__ qn, int qrs,
                 const float* __restrict__ qw, const float* __restrict__ cosb,
                 const float* __restrict__ sinb,
                 const short* __restrict__ kh, const short* __restrict__ kl,
                 const short* __restrict__ vtb, float* __restrict__ oA,
                 float* __restrict__ oB, float* __restrict__ mlA,
                 float* __restrict__ mlB) {
  __shared__ short Kh[32][256], Kl[32][256];  // 32 KB
  __shared__ short Vb[256][32];               // 16 KB
  __shared__ short Ps[64][32];                // 4 KB   (total 53248 B)
  const int qt = blockIdx.x, h = blockIdx.y, sp = blockIdx.z;
  const int kvh = h >> 1;
  const int q0 = qt * 64;
  const int tid = threadIdx.x;
  const int w = tid >> 6, lane = tid & 63;
  const int quad = lane >> 4, col = lane & 15;
  float* oOut = sp ? oB : oA;
  float* mlOut = sp ? mlB : mlA;
  short8 qh[8], ql[8];
  {
    const int sq = q0 + w * 16 + col;
    const float* qrow = qn + (size_t)sq * qrs + h * HD;
    float xq[8][8];
    float ssum = 0.f;
#pragma unroll
    for (int s8 = 0; s8 < 8; s8++) {
      const int d0 = s8 * 32 + quad * 8;
      float4_t a = *reinterpret_cast<const float4_t*>(qrow + d0);
      float4_t b = *reinterpret_cast<const float4_t*>(qrow + d0 + 4);
#pragma unroll
      for (int e = 0; e < 4; e++) {
        xq[s8][e] = a[e];
        xq[s8][4 + e] = b[e];
        ssum += a[e] * a[e] + b[e] * b[e];
      }
    }
    ssum += __shfl_xor(ssum, 16);
    ssum += __shfl_xor(ssum, 32);
    const float scale = rsqrtf(ssum * (1.0f / HD) + 1e-6f);
#pragma unroll
    for (int s8 = 0; s8 < 8; s8++) {
      const int d0 = s8 * 32 + quad * 8;
      float4_t w0 = *reinterpret_cast<const float4_t*>(qw + d0);
      float4_t w1 = *reinterpret_cast<const float4_t*>(qw + d0 + 4);
#pragma unroll
      for (int e = 0; e < 4; e++) {
        xq[s8][e] *= scale * w0[e];
        xq[s8][4 + e] *= scale * w1[e];
      }
    }
    const float* crow = cosb + (size_t)sq * HD;
    const float* srow = sinb + (size_t)sq * HD;
#pragma unroll
    for (int s8 = 0; s8 < 8; s8++) {
      const int d0 = s8 * 32 + quad * 8;
      float4_t c0 = *reinterpret_cast<const float4_t*>(crow + d0);
      float4_t c1 = *reinterpret_cast<const float4_t*>(crow + d0 + 4);
      float4_t s0 = *reinterpret_cast<const float4_t*>(srow + d0);
      float4_t s1 = *reinterpret_cast<const float4_t*>(srow + d0 + 4);
      const float sgn = (s8 < 4) ? -1.f : 1.f;
      const int pp = s8 ^ 4;
#pragma unroll
      for (int e = 0; e < 4; e++) {
        short hh, ll;
        split2(xq[s8][e] * c0[e] + sgn * xq[pp][e] * s0[e], hh, ll);
        qh[s8][e] = hh; ql[s8][e] = ll;
        split2(xq[s8][4 + e] * c1[e] + sgn * xq[pp][4 + e] * s1[e], hh, ll);
        qh[s8][4 + e] = hh; ql[s8][4 + e] = ll;
      }
    }
  }
  f32x4 o[16];
#pragma unroll
  for (int i = 0; i < 16; i++) o[i] = (f32x4){0.f, 0.f, 0.f, 0.f};
  float m_r[4] = {-INFINITY, -INFINITY, -INFINITY, -INFINITY};
  float l_r[4] = {0.f, 0.f, 0.f, 0.f};
  const int lo_t = (q0 > 1023) ? ((q0 - 1023) >> 5) : 0;
  const int hi_t = (q0 + 63) >> 5;
  const int halfn = (hi_t - lo_t + 2) >> 1;
  const int t0 = sp ? (lo_t + halfn) : lo_t;
  const int t1 = sp ? hi_t : (lo_t + halfn - 1);
  for (int kt = t0; kt <= t1; kt++) {
    const int kt0 = kt << 5;
    __syncthreads();
#pragma unroll
    for (int i = 0; i < 4; i++) {
      int idx = tid + i * 256;
      int row = idx >> 5, g = idx & 31;
      size_t gofs = ((size_t)(kt0 + row) * NKV + kvh) * HD + g * 8;
      *reinterpret_cast<short8*>(&Kh[row][KSW(g, row)]) =
          *reinterpret_cast<const short8*>(kh + gofs);
      *reinterpret_cast<short8*>(&Kl[row][KSW(g, row)]) =
          *reinterpret_cast<const short8*>(kl + gofs);
    }
#pragma unroll
    for (int i = 0; i < 4; i++) {
      int idx = tid + i * 256;
      int d = idx >> 2, g = idx & 3;
      *reinterpret_cast<short8*>(&Vb[d][VSW(g, d)]) =
          *reinterpret_cast<const short8*>(
              vtb + ((size_t)kvh * HD + d) * S_LEN + kt0 + g * 8);
    }
    __syncthreads();
    // QK^T with 6 independent MFMA chains: schh/schl/sclh x 2 nt
    f32x4 schh[2], schl[2], sclh[2];
#pragma unroll
    for (int nt = 0; nt < 2; nt++) {
      schh[nt] = (f32x4){0.f, 0.f, 0.f, 0.f};
      schl[nt] = (f32x4){0.f, 0.f, 0.f, 0.f};
      sclh[nt] = (f32x4){0.f, 0.f, 0.f, 0.f};
    }
    __builtin_amdgcn_s_setprio(1);
#pragma unroll
    for (int s8 = 0; s8 < 8; s8++) {
#pragma unroll
      for (int nt = 0; nt < 2; nt++) {
        const int br = nt * 16 + col;
        const short8 bh = *reinterpret_cast<const short8*>(
            &Kh[br][KSW(s8 * 4 + quad, br)]);
        const short8 bl = *reinterpret_cast<const short8*>(
            &Kl[br][KSW(s8 * 4 + quad, br)]);
        schh[nt] = __builtin_amdgcn_mfma_f32_16x16x32_bf16(qh[s8], bh, schh[nt], 0, 0, 0);
        schl[nt] = __builtin_amdgcn_mfma_f32_16x16x32_bf16(qh[s8], bl, schl[nt], 0, 0, 0);
        sclh[nt] = __builtin_amdgcn_mfma_f32_16x16x32_bf16(ql[s8], bh, sclh[nt], 0, 0, 0);
      }
    }
    __builtin_amdgcn_s_setprio(0);
    f32x4 sc[2];
#pragma unroll
    for (int nt = 0; nt < 2; nt++) sc[nt] = schh[nt] + schl[nt] + sclh[nt];
#pragma unroll
    for (int r = 0; r < 4; r++) {
      const int q_abs = q0 + w * 16 + quad * 4 + r;
      const int prow = w * 16 + quad * 4 + r;
#pragma unroll
      for (int nt = 0; nt < 2; nt++) {
        int k_abs = kt0 + nt * 16 + col;
        bool valid = (k_abs <= q_abs) && (q_abs - k_abs < WINDOW);
        if (!valid) sc[nt][r] = -INFINITY;
      }
      float mx = fmaxf(sc[0][r], sc[1][r]);
      mx = fmaxf(mx, __shfl_xor(mx, 1));
      mx = fmaxf(mx, __shfl_xor(mx, 2));
      mx = fmaxf(mx, __shfl_xor(mx, 4));
      mx = fmaxf(mx, __shfl_xor(mx, 8));
      // defer-max (T13): only rescale when the max moved by >8
      if (!__all(mx <= m_r[r] + 8.f)) {
        const float mn = fmaxf(m_r[r], mx);
        const float alpha = (mn == -INFINITY) ? 1.f : __expf(m_r[r] - mn);
        m_r[r] = mn;
        l_r[r] *= alpha;
#pragma unroll
        for (int nt2 = 0; nt2 < 16; nt2++) o[nt2][r] *= alpha;
      }
      float rsum = 0.f;
#pragma unroll
      for (int nt = 0; nt < 2; nt++) {
        float s = sc[nt][r];
        float e = (s == -INFINITY) ? 0.f : __expf(s - m_r[r]);
        rsum += e;
        int ge = nt * 2 + (col >> 3);
        Ps[prow][VSW(ge, prow) + (col & 7)] = bf16_rne(e);
      }
      rsum += __shfl_xor(rsum, 1);
      rsum += __shfl_xor(rsum, 2);
      rsum += __shfl_xor(rsum, 4);
      rsum += __shfl_xor(rsum, 8);
      l_r[r] += rsum;
    }
    __syncthreads();
    {
      const int prow = w * 16 + col;
      const short8 pa = *reinterpret_cast<const short8*>(&Ps[prow][VSW(quad, prow)]);
      __builtin_amdgcn_s_setprio(1);
#pragma unroll
      for (int nt = 0; nt < 16; nt++) {
        const int vr = nt * 16 + col;
        const short8 vb = *reinterpret_cast<const short8*>(&Vb[vr][VSW(quad, vr)]);
        o[nt] = __builtin_amdgcn_mfma_f32_16x16x32_bf16(pa, vb, o[nt], 0, 0, 0);
      }
      __builtin_amdgcn_s_setprio(0);
    }
  }
#pragma unroll
  for (int r = 0; r < 4; r++) {
    const int row = q0 + w * 16 + quad * 4 + r;
    const size_t base = ((size_t)row * NH + h) * HD;
#pragma unroll
    for (int nt = 0; nt < 16; nt++) oOut[base + nt * 16 + col] = o[nt][r];
    if (col == 0) {
      mlOut[((size_t)row * NH + h) * 2] = m_r[r];
      mlOut[((size_t)row * NH + h) * 2 + 1] = l_r[r];
    }
  }
}

// merge the two k-splits -> single-bf16 ctx (out-proj A operand)
__global__ __launch_bounds__(256)
void combine_kernel(const float* __restrict__ oA, const float* __restrict__ oB,
                    const float* __restrict__ mlA, const float* __restrict__ mlB,
                    short* __restrict__ ctxh) {
  const int unit = blockIdx.x * 8 + (threadIdx.x >> 5);
  const int t = threadIdx.x & 31;
  const float mA = mlA[(size_t)unit * 2], lA = mlA[(size_t)unit * 2 + 1];
  const float mB = mlB[(size_t)unit * 2], lB = mlB[(size_t)unit * 2 + 1];
  const float m = fmaxf(mA, mB);
  const float eA = (mA == -INFINITY) ? 0.f : __expf(mA - m);
  const float eB = (mB == -INFINITY) ? 0.f : __expf(mB - m);
  const float inv = 1.0f / (eA * lA + eB * lB);
  const size_t b = (size_t)unit * HD + t * 8;
  const float4_t a0 = *reinterpret_cast<const float4_t*>(oA + b);
  const float4_t a1 = *reinterpret_cast<const float4_t*>(oA + b + 4);
  const float4_t b0 = *reinterpret_cast<const float4_t*>(oB + b);
  const float4_t b1 = *reinterpret_cast<const float4_t*>(oB + b + 4);
  short8 out;
#pragma unroll
  for (int e = 0; e < 4; e++) {
    out[e] = bf16_rne((eA * a0[e] + eB * b0[e]) * inv);
    out[4 + e] = bf16_rne((eA * a1[e] + eB * b1[e]) * inv);
  }
  *reinterpret_cast<short8*>(ctxh + b) = out;
}

extern "C" void kernel_launch(void* const* d_in, const int* in_sizes, int n_in,
                              void* d_out, int out_size, void* d_ws, size_t ws_size,
                              hipStream_t stream) {
  const float* hs   = (const float*)d_in[0];
  const float* cosb = (const float*)d_in[1];
  const float* sinb = (const float*)d_in[2];
  const float* wq   = (const float*)d_in[3];
  const float* wk   = (const float*)d_in[4];
  const float* wv   = (const float*)d_in[5];
  const float* wo   = (const float*)d_in[6];
  const float* qw   = (const float*)d_in[7];
  const float* kw   = (const float*)d_in[8];
  dim3 blk(256);

  const size_t szAh   = (size_t)S_LEN * HID * 2;       // 10.49 MB
  const size_t szQKVT = (size_t)4096 * HID * 2;        // 20.97 MB
  const size_t szWoT  = (size_t)HID * 2048 * 2;        // 10.49 MB
  const size_t szCqkv = (size_t)S_LEN * 4096 * 4;      // 33.55 MB
  const size_t szKh   = (size_t)S_LEN * NKV * HD * 2;  // 4.19 MB
  const size_t szMl   = (size_t)S_LEN * NH * 2 * 4;    // 131 KB

  char* p = (char*)d_ws + 256;
  short* Ah    = (short*)p;  p += szAh;    // later: oA fp32 (16.8 MB <= Ah+Al 21 MB)
  short* Al    = (short*)p;  p += szAh;
  short* qkvTh = (short*)p;  p += szQKVT;  // later: ctxh bf16 (8.4 MB)
  short* qkvTl = (short*)p;  p += szQKVT;
  short* woTh  = (short*)p;  p += szWoT;
  short* woTl  = (short*)p;  p += szWoT;
  float* Cqkv  = (float*)p;  p += szCqkv;
  short* kh    = (short*)p;  p += szKh;
  short* kl    = (short*)p;  p += szKh;
  short* vtb   = (short*)p;  p += szKh;
  float* mlA   = (float*)p;  p += szMl;
  float* mlB   = (float*)p;  p += szMl;
  float* oA    = (float*)Ah;      // alias: Ah/Al dead after GEMMs
  float* oB    = (float*)d_out;   // dead until out-proj
  short* ctxh  = qkvTh;           // alias: qkvT dead after qkv GEMM

  // merged prep: hs split + wq/wk/wv/wo splitT
  prep_kernel<<<8960, blk, 0, stream>>>(hs, wq, wk, wv, wo, Ah, Al, qkvTh,
                                        qkvTl, woTh, woTl);
  // merged qkv projection (v MODE2 first, then qk MODE3; 1024 blocks)
  gemm_qkv<<<1024, blk, 0, stream>>>(Ah, Al, qkvTh, qkvTl, Cqkv);
  // merged k/v norms, wave-per-row
  norm_kernel<<<4096, blk, 0, stream>>>(Cqkv, kw, cosb, sinb, kh, kl, vtb);
  // flash attention (split-k x2), q-norm+rope fused, 6-chain QK + setprio
  flash_attn2<<<dim3(S_LEN / 64, NH, 2), blk, 0, stream>>>(
      Cqkv, 4096, qw, cosb, sinb, kh, kl, vtb, oA, oB, mlA, mlB);
  combine_kernel<<<2048, blk, 0, stream>>>(oA, oB, mlA, mlB, ctxh);
  // out projection: 128x128 tile, 320 blocks, single residency wave
  gemm_out128<<<320, blk, 0, stream>>>(ctxh, woTh, woTl, (float*)d_out);
}